// Round 6
// baseline (1403.126 us; speedup 1.0000x reference)
//
#include <hip/hip_runtime.h>

#define NNODES 50000
#define NEDGES 800000

typedef __bf16 bf16x8 __attribute__((ext_vector_type(8)));
typedef short short8 __attribute__((ext_vector_type(8)));
typedef float f32x4 __attribute__((ext_vector_type(4)));

// ws layout (byte offsets):
#define OFF_FE_W0T 0        // short idx
#define OFF_FE_W1T 81920
#define OFF_FE_W2T 147456
#define OFF_FN_W0T 180224
#define OFF_FN_W1T 245760
#define OFF_FN_W2T 311296   // ends at short 344064 = byte 688128
#define OFF_CNT_B    688128              // int[50000]
#define OFF_BASE_B   888128              // int[50001]
#define OFF_CURSOR_B 1088384             // int[50000]
#define OFF_EIDX_B   1288448             // int[800000]
#define OFF_BSUM_B   4488448             // int[64]
#define OFF_NBF_B    4488704             // short[50000*128] bf16 node table (12.8 MB)

__device__ __forceinline__ short f2bf(float f) {
  union { float f; unsigned u; } v; v.f = f;
  unsigned r = v.u + 0x7FFFu + ((v.u >> 16) & 1u);   // RNE
  return (short)(r >> 16);
}

template <int MF, int NREP>
__device__ __forceinline__ void zero_acc(f32x4 acc[MF][NREP]) {
#pragma unroll
  for (int m = 0; m < MF; ++m)
#pragma unroll
    for (int n = 0; n < NREP; ++n)
      acc[m][n] = (f32x4){0.f, 0.f, 0.f, 0.f};
}

// Fused GEMM layer over a (MF*16)-row LDS tile. Wave wn computes all rows x
// cols [wn*NREP*16, +NREP*16). A = LDS (XOR-swizzled); B = global Wt [N][K]
// bf16 (L2-resident). Depth-1 B prefetch.
template <int KSTEPS, int MF, int NREP, int LDB, int WTK>
__device__ __forceinline__ void gemm_layer(const short* lds, const short* Wt,
                                           int wn, int lane, f32x4 acc[MF][NREP]) {
  const int m0 = lane & 15;
  const int g = lane >> 4;
  const short* wp = Wt + (wn * (NREP * 16) + m0) * WTK + g * 8;
  bf16x8 bcur[NREP], bnxt[NREP], a[MF];
#pragma unroll
  for (int n = 0; n < NREP; ++n) bcur[n] = *(const bf16x8*)(wp + n * 16 * WTK);
#pragma unroll
  for (int ks = 0; ks < KSTEPS; ++ks) {
    if (ks + 1 < KSTEPS) {
#pragma unroll
      for (int n = 0; n < NREP; ++n)
        bnxt[n] = *(const bf16x8*)(wp + (ks + 1) * 32 + n * 16 * WTK);
    }
    const int kb = ks * 32 + g * 8;
#pragma unroll
    for (int m = 0; m < MF; ++m) {
      int row = m * 16 + m0;
      int byte = row * LDB + kb * 2;
      byte ^= (row & 7) << 4;
      a[m] = *(const bf16x8*)((const char*)lds + byte);
    }
#pragma unroll
    for (int n = 0; n < NREP; ++n)
#pragma unroll
      for (int m = 0; m < MF; ++m)
        acc[m][n] = __builtin_amdgcn_mfma_f32_16x16x32_bf16(a[m], bcur[n], acc[m][n], 0, 0, 0);
#pragma unroll
    for (int n = 0; n < NREP; ++n) bcur[n] = bnxt[n];
  }
}

// bias + relu + bf16 + write back to LDS (swizzled) for the next layer.
template <int MF, int NREP, int LDB>
__device__ __forceinline__ void store_h(short* lds, const float* __restrict__ bias,
                                        int wn, int lane, f32x4 acc[MF][NREP]) {
  const int m0 = lane & 15;
  const int g = lane >> 4;
#pragma unroll
  for (int n = 0; n < NREP; ++n) {
    int col = wn * (NREP * 16) + n * 16 + m0;
    float bv = bias[col];
#pragma unroll
    for (int m = 0; m < MF; ++m) {
#pragma unroll
      for (int j = 0; j < 4; ++j) {
        int row = m * 16 + g * 4 + j;
        float v = acc[m][n][j] + bv;
        v = fmaxf(v, 0.f);
        int byte = row * LDB + col * 2;
        byte ^= (row & 7) << 4;
        *(short*)((char*)lds + byte) = f2bf(v);
      }
    }
  }
}

// Final layer (128 cols): acc -> LDS f32 [ROWS][128] (swizzled) -> streaming
// full-row float4 stores. rowmap maps tile row -> global row (<0 skips).
template <int MF, int NOUT, int ROWS, int T, typename F>
__device__ __forceinline__ void coalesced_out(float* fl, const float* __restrict__ bias,
                                              int wn, int tid, int lane,
                                              f32x4 acc[MF][NOUT], float* __restrict__ gout,
                                              F rowmap) {
  const int m0 = lane & 15;
  const int g = lane >> 4;
#pragma unroll
  for (int n = 0; n < NOUT; ++n) {
    int col = wn * (NOUT * 16) + n * 16 + m0;
    float bv = bias[col];
#pragma unroll
    for (int m = 0; m < MF; ++m) {
#pragma unroll
      for (int j = 0; j < 4; ++j) {
        int row = m * 16 + g * 4 + j;
        int byte = (row * 128 + col) * 4;
        byte ^= (row & 7) << 4;
        *(float*)((char*)fl + byte) = acc[m][n][j] + bv;
      }
    }
  }
  __syncthreads();
  constexpr int QN = (ROWS * 128) / (T * 4);
#pragma unroll
  for (int q = 0; q < QN; ++q) {
    int idx = q * (T * 4) + tid * 4;
    int row = idx >> 7;
    long grow = rowmap(row);
    if (grow < 0) continue;
    int byte = (idx * 4) ^ ((row & 7) << 4);
    float4 v = *(const float4*)((const char*)fl + byte);
    *(float4*)(gout + grow * 128 + (idx & 127)) = v;
  }
}

// Transpose+cast all 6 weight matrices f32 [K][N] -> bf16 [N][K] into ws.
__global__ void prep_weights_all(const float* __restrict__ w0, const float* __restrict__ w1,
                                 const float* __restrict__ w2, const float* __restrict__ w3,
                                 const float* __restrict__ w4, const float* __restrict__ w5,
                                 short* __restrict__ wsw) {
  const float* src; short* dst; int K, N;
  switch (blockIdx.y) {
    case 0: src = w0; dst = wsw + OFF_FE_W0T; K = 320; N = 256; break;
    case 1: src = w1; dst = wsw + OFF_FE_W1T; K = 256; N = 256; break;
    case 2: src = w2; dst = wsw + OFF_FE_W2T; K = 256; N = 128; break;
    case 3: src = w3; dst = wsw + OFF_FN_W0T; K = 256; N = 256; break;
    case 4: src = w4; dst = wsw + OFF_FN_W1T; K = 256; N = 256; break;
    default: src = w5; dst = wsw + OFF_FN_W2T; K = 256; N = 128; break;
  }
  int idx = blockIdx.x * 256 + threadIdx.x;
  if (idx < K * N) {
    int k = idx / N;
    int n = idx - k * N;
    dst[n * K + k] = f2bf(src[idx]);
  }
}

// f32 -> bf16 cast, 8 elements/thread (node feature table).
__global__ void cvt_bf16(const float* __restrict__ src, short* __restrict__ dst, int n8) {
  int i = blockIdx.x * 256 + threadIdx.x;
  if (i < n8) {
    float4 v0 = ((const float4*)src)[i * 2];
    float4 v1 = ((const float4*)src)[i * 2 + 1];
    short8 pk;
    pk[0] = f2bf(v0.x); pk[1] = f2bf(v0.y); pk[2] = f2bf(v0.z); pk[3] = f2bf(v0.w);
    pk[4] = f2bf(v1.x); pk[5] = f2bf(v1.y); pk[6] = f2bf(v1.z); pk[7] = f2bf(v1.w);
    ((short8*)dst)[i] = pk;
  }
}

// ---- CSR build: histogram -> 3-phase parallel scan -> scatter ----
__global__ void hist_kernel(const int* __restrict__ receivers, int* __restrict__ cnt) {
  int e = blockIdx.x * 512 + threadIdx.x;
  if (e < NEDGES) atomicAdd(&cnt[receivers[e]], 1);
}

__global__ __launch_bounds__(1024) void scan1_kernel(const int* __restrict__ cnt,
                                                     int* __restrict__ base,
                                                     int* __restrict__ bsum) {
  __shared__ int s[1024];
  const int tid = threadIdx.x;
  int i = blockIdx.x * 1024 + tid;
  int v = (i < NNODES) ? cnt[i] : 0;
  s[tid] = v;
  __syncthreads();
  for (int off = 1; off < 1024; off <<= 1) {
    int t = (tid >= off) ? s[tid - off] : 0;
    __syncthreads();
    s[tid] += t;
    __syncthreads();
  }
  if (i < NNODES) base[i] = s[tid] - v;     // exclusive within block
  if (tid == 1023) bsum[blockIdx.x] = s[1023];
}

__global__ void scan2_kernel(int* __restrict__ bsum, int nblk) {
  if (threadIdx.x == 0) {
    int run = 0;
    for (int b = 0; b < nblk; ++b) { int t = bsum[b]; bsum[b] = run; run += t; }
  }
}

__global__ __launch_bounds__(1024) void scan3_kernel(const int* __restrict__ bsum,
                                                     int* __restrict__ base,
                                                     int* __restrict__ cursor) {
  int i = blockIdx.x * 1024 + threadIdx.x;
  if (i < NNODES) {
    int b = base[i] + bsum[blockIdx.x];
    base[i] = b;
    cursor[i] = b;
  }
  if (i == 0) base[NNODES] = NEDGES;
}

__global__ void scatter_kernel(const int* __restrict__ receivers, int* __restrict__ cursor,
                               int* __restrict__ eidx) {
  int e = blockIdx.x * 512 + threadIdx.x;
  if (e < NEDGES) {
    int pos = atomicAdd(&cursor[receivers[e]], 1);
    eidx[pos] = e;
  }
}

// Fused 3-layer edge MLP over a 32-edge tile (natural order), 4 waves, NREP=4.
// 20 KB LDS + ~100 regs -> 4-5 independent blocks/CU for barrier overlap.
__global__ __launch_bounds__(256, 4) void edge_kernel(
    const short* __restrict__ nbf, const float* __restrict__ edge_attrs,
    const int* __restrict__ senders, const int* __restrict__ receivers,
    const short* __restrict__ wsw,
    const float* __restrict__ b0, const float* __restrict__ b1,
    const float* __restrict__ b2, float* __restrict__ e_out) {
  __shared__ short lds[10240];  // 20480 B: [32][320] bf16; reused for h and f32 repack
  const int tid = threadIdx.x;
  const int lane = tid & 63;
  const int wn = tid >> 6;      // 0..3
  const int e0 = blockIdx.x * 32;

  // ---- stage X = [ns(128) | nr(128) | ea(64)] bf16 [32][320], swizzled ----
  // 1280 16B-chunks; node features copied bf16->bf16.
#pragma unroll
  for (int i = 0; i < 5; ++i) {
    int task = i * 256 + tid;
    int row = task / 40;
    int c = task - row * 40;
    int erow = e0 + row;
    short8 pk;
    if (c < 32) {
      const short* p = (c < 16) ? nbf + (size_t)senders[erow] * 128 + c * 8
                                : nbf + (size_t)receivers[erow] * 128 + (c - 16) * 8;
      pk = *(const short8*)p;
    } else {
      const float* p = edge_attrs + (size_t)erow * 64 + (c - 32) * 8;
      float4 v0 = *(const float4*)p;
      float4 v1 = *(const float4*)(p + 4);
      pk[0] = f2bf(v0.x); pk[1] = f2bf(v0.y); pk[2] = f2bf(v0.z); pk[3] = f2bf(v0.w);
      pk[4] = f2bf(v1.x); pk[5] = f2bf(v1.y); pk[6] = f2bf(v1.z); pk[7] = f2bf(v1.w);
    }
    int byte = row * 640 + c * 16;
    byte ^= (row & 7) << 4;
    *(short8*)((char*)lds + byte) = pk;
  }
  __syncthreads();

  f32x4 acc[2][4];
  zero_acc<2, 4>(acc);
  gemm_layer<10, 2, 4, 640, 320>(lds, wsw + OFF_FE_W0T, wn, lane, acc);
  __syncthreads();
  store_h<2, 4, 512>(lds, b0, wn, lane, acc);
  __syncthreads();

  zero_acc<2, 4>(acc);
  gemm_layer<8, 2, 4, 512, 256>(lds, wsw + OFF_FE_W1T, wn, lane, acc);
  __syncthreads();
  store_h<2, 4, 512>(lds, b1, wn, lane, acc);
  __syncthreads();

  f32x4 acc2[2][2];
  zero_acc<2, 2>(acc2);
  gemm_layer<8, 2, 2, 512, 256>(lds, wsw + OFF_FE_W2T, wn, lane, acc2);
  __syncthreads();

  coalesced_out<2, 2, 32, 256>((float*)lds, b2, wn, tid, lane, acc2, e_out,
                               [&](int row) -> long { return (long)(e0 + row); });
}

// Fused 3-layer node MLP over a 64-node tile, 8 waves, NREP=2 (unchanged from r5).
__global__ __launch_bounds__(512, 4) void node_kernel(
    const short* __restrict__ nbf, const float* __restrict__ e_out,
    const int* __restrict__ basep, const int* __restrict__ eidx,
    const short* __restrict__ wsw,
    const float* __restrict__ b0, const float* __restrict__ b1,
    const float* __restrict__ b2, float* __restrict__ n_out) {
  __shared__ short lds[16384];  // 32 KiB: [64][256] bf16; reused for f32 repack
  const int tid = threadIdx.x;
  const int lane = tid & 63;
  const int wn = tid >> 6;
  const int r0 = blockIdx.x * 64;

  // ---- stage node bf16 features -> cols 0..127 (1024 16B-chunks) ----
#pragma unroll
  for (int i = 0; i < 2; ++i) {
    int task = i * 512 + tid;
    int row = task >> 4;
    int c = task & 15;
    int nrow = r0 + row;
    if (nrow >= NNODES) nrow = NNODES - 1;
    short8 pk = *(const short8*)(nbf + (size_t)nrow * 128 + c * 8);
    int byte = row * 512 + c * 16;
    byte ^= (row & 7) << 4;
    *(short8*)((char*)lds + byte) = pk;
  }

  // ---- CSR gather-sum: in_edges -> cols 128..255 ----
  {
    const int n_local = tid >> 3;       // 0..63
    const int cg = tid & 7;             // 16-col group
    const int node = r0 + n_local;
    float sum[16];
#pragma unroll
    for (int q = 0; q < 16; ++q) sum[q] = 0.f;
    if (node < NNODES) {
      int beg = basep[node], end = basep[node + 1];
      for (int j = beg; j < end; ++j) {
        int e = eidx[j];
        const float* er = e_out + (size_t)e * 128 + cg * 16;
#pragma unroll
        for (int q = 0; q < 4; ++q) {
          float4 v = *(const float4*)(er + q * 4);
          sum[q * 4 + 0] += v.x; sum[q * 4 + 1] += v.y;
          sum[q * 4 + 2] += v.z; sum[q * 4 + 3] += v.w;
        }
      }
    }
#pragma unroll
    for (int q = 0; q < 2; ++q) {
      short8 pk;
#pragma unroll
      for (int k = 0; k < 8; ++k) pk[k] = f2bf(sum[q * 8 + k]);
      int col = 128 + cg * 16 + q * 8;
      int byte = n_local * 512 + col * 2;
      byte ^= (n_local & 7) << 4;
      *(short8*)((char*)lds + byte) = pk;
    }
  }
  __syncthreads();

  f32x4 acc[4][2];
  zero_acc<4, 2>(acc);
  gemm_layer<8, 4, 2, 512, 256>(lds, wsw + OFF_FN_W0T, wn, lane, acc);
  __syncthreads();
  store_h<4, 2, 512>(lds, b0, wn, lane, acc);
  __syncthreads();

  zero_acc<4, 2>(acc);
  gemm_layer<8, 4, 2, 512, 256>(lds, wsw + OFF_FN_W1T, wn, lane, acc);
  __syncthreads();
  store_h<4, 2, 512>(lds, b1, wn, lane, acc);
  __syncthreads();

  f32x4 acc2[4][1];
  zero_acc<4, 1>(acc2);
  gemm_layer<8, 4, 1, 512, 256>(lds, wsw + OFF_FN_W2T, wn, lane, acc2);
  __syncthreads();

  coalesced_out<4, 1, 64, 512>((float*)lds, b2, wn, tid, lane, acc2, n_out,
                               [&](int row) -> long {
                                 long g = r0 + row;
                                 return (g < NNODES) ? g : -1;
                               });
}

extern "C" void kernel_launch(void* const* d_in, const int* in_sizes, int n_in,
                              void* d_out, int out_size, void* d_ws, size_t ws_size,
                              hipStream_t stream) {
  const float* node_attrs = (const float*)d_in[0];
  const float* edge_attrs = (const float*)d_in[1];
  const int* senders = (const int*)d_in[2];
  const int* receivers = (const int*)d_in[3];
  const float* fe_W0 = (const float*)d_in[4];
  const float* fe_b0 = (const float*)d_in[5];
  const float* fe_W1 = (const float*)d_in[6];
  const float* fe_b1 = (const float*)d_in[7];
  const float* fe_W2 = (const float*)d_in[8];
  const float* fe_b2 = (const float*)d_in[9];
  const float* fn_W0 = (const float*)d_in[10];
  const float* fn_b0 = (const float*)d_in[11];
  const float* fn_W1 = (const float*)d_in[12];
  const float* fn_b1 = (const float*)d_in[13];
  const float* fn_W2 = (const float*)d_in[14];
  const float* fn_b2 = (const float*)d_in[15];

  short* wsw  = (short*)d_ws;
  int* cnt    = (int*)((char*)d_ws + OFF_CNT_B);
  int* basep  = (int*)((char*)d_ws + OFF_BASE_B);
  int* cursor = (int*)((char*)d_ws + OFF_CURSOR_B);
  int* eidx   = (int*)((char*)d_ws + OFF_EIDX_B);
  int* bsum   = (int*)((char*)d_ws + OFF_BSUM_B);
  short* nbf  = (short*)((char*)d_ws + OFF_NBF_B);
  float* out = (float*)d_out;
  float* n_out = out;                                  // [50000][128] first
  float* e_out = out + (size_t)NNODES * 128;           // then [800000][128]

  dim3 gprep(320, 6);
  prep_weights_all<<<gprep, 256, 0, stream>>>(fe_W0, fe_W1, fe_W2, fn_W0, fn_W1, fn_W2, wsw);
  cvt_bf16<<<(NNODES * 128 / 8 + 255) / 256, 256, 0, stream>>>(node_attrs, nbf, NNODES * 128 / 8);
  hipMemsetAsync(cnt, 0, NNODES * sizeof(int), stream);

  const int nscan = (NNODES + 1023) / 1024;   // 49
  hist_kernel<<<(NEDGES + 511) / 512, 512, 0, stream>>>(receivers, cnt);
  scan1_kernel<<<nscan, 1024, 0, stream>>>(cnt, basep, bsum);
  scan2_kernel<<<1, 64, 0, stream>>>(bsum, nscan);
  scan3_kernel<<<nscan, 1024, 0, stream>>>(bsum, basep, cursor);
  scatter_kernel<<<(NEDGES + 511) / 512, 512, 0, stream>>>(receivers, cursor, eidx);

  edge_kernel<<<NEDGES / 32, 256, 0, stream>>>(nbf, edge_attrs, senders, receivers,
                                               wsw, fe_b0, fe_b1, fe_b2, e_out);
  node_kernel<<<(NNODES + 63) / 64, 512, 0, stream>>>(nbf, e_out, basep, eidx, wsw,
                                                      fn_b0, fn_b1, fn_b2, n_out);
}

// Round 7
// 1017.838 us; speedup vs baseline: 1.3785x; 1.3785x over previous
//
#include <hip/hip_runtime.h>

#define NNODES 50000
#define NEDGES 800000

typedef __bf16 bf16x8 __attribute__((ext_vector_type(8)));
typedef short short8 __attribute__((ext_vector_type(8)));
typedef float f32x4 __attribute__((ext_vector_type(4)));

// ws layout (byte offsets):
#define OFF_FE_W0T 0        // short idx
#define OFF_FE_W1T 81920
#define OFF_FE_W2T 147456
#define OFF_FN_W0T 180224
#define OFF_FN_W1T 245760
#define OFF_FN_W2T 311296   // ends at short 344064 = byte 688128
#define OFF_CNT_B    688128              // int[50000]
#define OFF_BASE_B   888128              // int[50001]
#define OFF_CURSOR_B 1088384             // int[50000]
#define OFF_EIDX_B   1288448             // int[800000]
#define OFF_BSUM_B   4488448             // int[64]
#define OFF_NBF_B    4488704             // short[50000*128] bf16 node table (12.8 MB)

__device__ __forceinline__ short f2bf(float f) {
  union { float f; unsigned u; } v; v.f = f;
  unsigned r = v.u + 0x7FFFu + ((v.u >> 16) & 1u);   // RNE
  return (short)(r >> 16);
}

typedef const unsigned __attribute__((address_space(1)))* gas_t;
typedef unsigned __attribute__((address_space(3)))* las_t;
__device__ __forceinline__ void gload16(const short* g, short* l) {
  __builtin_amdgcn_global_load_lds((gas_t)(const void*)g, (las_t)(void*)l, 16, 0, 0);
}

// ---------------- edge kernel (W-through-LDS pipeline) ----------------
// LDS map (bytes): X/h [128][640->512] @0 (80KB); W ring 2 x 32KB @81920..147456.
// W slice layout: [NW rows][128B = 8 chunks of 16B], chunk sl of row n holds
// W[n][kbase + (sl^(n&7))*8 .. +8]  (2 K-steps of 32 elems = 64 elems per slice).
template <int NW, int WTK>
__device__ __forceinline__ void stage_w(const short* __restrict__ Wt, int kbase,
                                        short* slot, int wid, int lane) {
  constexpr int ROUNDS = (NW * 128) / 8192;   // 256 rows -> 4, 128 rows -> 2
#pragma unroll
  for (int r = 0; r < ROUNDS; ++r) {
    int f = (r * 8 + wid) * 64 + lane;        // 16B-chunk index, lane-linear
    int n = f >> 3;
    int sl = f & 7;
    const short* src = Wt + n * WTK + kbase + ((sl ^ (n & 7)) << 3);
    short* dst = slot + (size_t)(r * 8 + wid) * 512;   // wave-uniform; +lane*16 by HW
    gload16(src, dst);
  }
}

// Compute one 2-K-step slice. Wave (wr,wc): rows wr*64 + m*16 (MF=4),
// cols wc*(NREP*16) + n*16. A from X LDS (xor (row&7)<<4), B from W slot.
template <int NREP, int LDB>
__device__ __forceinline__ void compute_pair(const short* xl, const short* wslot,
                                             int kk0, int wr, int wc, int lane,
                                             f32x4 acc[4][NREP]) {
  const int m0 = lane & 15;
  const int g = lane >> 4;
#pragma unroll
  for (int p = 0; p < 2; ++p) {
    const int kk = kk0 + p;
    bf16x8 a[4], b[NREP];
#pragma unroll
    for (int m = 0; m < 4; ++m) {
      int row = wr * 64 + m * 16 + m0;
      int byte = row * LDB + kk * 64 + g * 16;
      byte ^= (row & 7) << 4;
      a[m] = *(const bf16x8*)((const char*)xl + byte);
    }
#pragma unroll
    for (int n = 0; n < NREP; ++n) {
      int col = wc * (NREP * 16) + n * 16 + m0;
      int byte = col * 128 + (((p * 4 + g) ^ (col & 7)) << 4);
      b[n] = *(const bf16x8*)((const char*)wslot + byte);
    }
#pragma unroll
    for (int n = 0; n < NREP; ++n)
#pragma unroll
      for (int m = 0; m < 4; ++m)
        acc[m][n] = __builtin_amdgcn_mfma_f32_16x16x32_bf16(a[m], b[n], acc[m][n], 0, 0, 0);
  }
}

// bias + relu + bf16 -> X LDS [rows][LDB] (swizzled) for the next layer.
template <int NREP, int LDB>
__device__ __forceinline__ void store_h2(short* xl, const float* __restrict__ bias,
                                         int wr, int wc, int lane, f32x4 acc[4][NREP]) {
  const int m0 = lane & 15;
  const int g = lane >> 4;
#pragma unroll
  for (int n = 0; n < NREP; ++n) {
    int col = wc * (NREP * 16) + n * 16 + m0;
    float bv = bias[col];
#pragma unroll
    for (int m = 0; m < 4; ++m) {
#pragma unroll
      for (int j = 0; j < 4; ++j) {
        int row = wr * 64 + m * 16 + g * 4 + j;
        float v = acc[m][n][j] + bv;
        v = fmaxf(v, 0.f);
        int byte = row * LDB + col * 2;
        byte ^= (row & 7) << 4;
        *(short*)((char*)xl + byte) = f2bf(v);
      }
    }
  }
}

// acc -> LDS f32 [ROWS][128] (swizzled) -> streaming full-row float4 stores.
template <int NOUT, int ROWS, int T, typename F>
__device__ __forceinline__ void coalesced_out(float* fl, const float* __restrict__ bias,
                                              int wr, int wc, int tid, int lane,
                                              f32x4 acc[4][NOUT], float* __restrict__ gout,
                                              F rowmap) {
  const int m0 = lane & 15;
  const int g = lane >> 4;
#pragma unroll
  for (int n = 0; n < NOUT; ++n) {
    int col = wc * (NOUT * 16) + n * 16 + m0;
    float bv = bias[col];
#pragma unroll
    for (int m = 0; m < 4; ++m) {
#pragma unroll
      for (int j = 0; j < 4; ++j) {
        int row = wr * 64 + m * 16 + g * 4 + j;
        int byte = (row * 128 + col) * 4;
        byte ^= (row & 7) << 4;
        *(float*)((char*)fl + byte) = acc[m][n][j] + bv;
      }
    }
  }
  __syncthreads();
  constexpr int QN = (ROWS * 128) / (T * 4);
#pragma unroll
  for (int q = 0; q < QN; ++q) {
    int idx = q * (T * 4) + tid * 4;
    int row = idx >> 7;
    long grow = rowmap(row);
    if (grow < 0) continue;
    int byte = (idx * 4) ^ ((row & 7) << 4);
    float4 v = *(const float4*)((const char*)fl + byte);
    *(float4*)(gout + grow * 128 + (idx & 127)) = v;
  }
}

__global__ __launch_bounds__(512, 2) void edge_kernel(
    const short* __restrict__ nbf, const float* __restrict__ edge_attrs,
    const int* __restrict__ senders, const int* __restrict__ receivers,
    const short* __restrict__ wsw,
    const float* __restrict__ b0, const float* __restrict__ b1,
    const float* __restrict__ b2, float* __restrict__ e_out) {
  __shared__ short lds[73728];            // 147456 B
  short* xl = lds;                         // X/h: 80 KB
  short* slot[2] = {lds + 40960, lds + 40960 + 16384};  // 2 x 32 KB W ring
  const int tid = threadIdx.x;
  const int lane = tid & 63;
  const int wid = tid >> 6;
  const int wr = wid >> 2, wc = wid & 3;
  const int e0 = blockIdx.x * 128;
  const short* w0t = wsw + OFF_FE_W0T;
  const short* w1t = wsw + OFF_FE_W1T;
  const short* w2t = wsw + OFF_FE_W2T;

  // Issue first W slice immediately (hides under the gather below).
  stage_w<256, 320>(w0t, 0, slot[0], wid, lane);

  // ---- stage X = [ns(128) | nr(128) | ea(64)] bf16 [128][320], swizzled ----
#pragma unroll
  for (int i = 0; i < 10; ++i) {
    int task = i * 512 + tid;       // 5120 16B-chunks
    int row = task / 40;
    int c = task - row * 40;
    int erow = e0 + row;
    short8 pk;
    if (c < 32) {
      const short* p = (c < 16) ? nbf + (size_t)senders[erow] * 128 + c * 8
                                : nbf + (size_t)receivers[erow] * 128 + (c - 16) * 8;
      pk = *(const short8*)p;
    } else {
      const float* p = edge_attrs + (size_t)erow * 64 + (c - 32) * 8;
      float4 v0 = *(const float4*)p;
      float4 v1 = *(const float4*)(p + 4);
      pk[0] = f2bf(v0.x); pk[1] = f2bf(v0.y); pk[2] = f2bf(v0.z); pk[3] = f2bf(v0.w);
      pk[4] = f2bf(v1.x); pk[5] = f2bf(v1.y); pk[6] = f2bf(v1.z); pk[7] = f2bf(v1.w);
    }
    int byte = row * 640 + c * 16;
    byte ^= (row & 7) << 4;
    *(short8*)((char*)xl + byte) = pk;
  }
  asm volatile("s_waitcnt vmcnt(0)" ::: "memory");
  __syncthreads();

  // ---- L0: 5 slices (stages 0..4), K=320, LDB=640 ----
  f32x4 acc[4][4];
#pragma unroll
  for (int m = 0; m < 4; ++m)
#pragma unroll
    for (int n = 0; n < 4; ++n) acc[m][n] = (f32x4){0.f, 0.f, 0.f, 0.f};
#pragma unroll
  for (int s = 0; s < 5; ++s) {
    if (s < 4) stage_w<256, 320>(w0t, (s + 1) * 64, slot[(s + 1) & 1], wid, lane);
    else       stage_w<256, 256>(w1t, 0, slot[1], wid, lane);       // stage 5 -> slot 1
    compute_pair<4, 640>(xl, slot[s & 1], s * 2, wr, wc, lane, acc);
    asm volatile("s_waitcnt vmcnt(0)" ::: "memory");
    __syncthreads();
  }
  store_h2<4, 512>(xl, b0, wr, wc, lane, acc);
  __syncthreads();

  // ---- L1: 4 slices (stages 5..8), K=256, LDB=512 ----
#pragma unroll
  for (int m = 0; m < 4; ++m)
#pragma unroll
    for (int n = 0; n < 4; ++n) acc[m][n] = (f32x4){0.f, 0.f, 0.f, 0.f};
#pragma unroll
  for (int s = 0; s < 4; ++s) {
    const int st = 5 + s;
    if (s < 3) stage_w<256, 256>(w1t, (s + 1) * 64, slot[(st + 1) & 1], wid, lane);
    else       stage_w<128, 256>(w2t, 0, slot[1], wid, lane);       // stage 9 -> slot 1
    compute_pair<4, 512>(xl, slot[st & 1], s * 2, wr, wc, lane, acc);
    asm volatile("s_waitcnt vmcnt(0)" ::: "memory");
    __syncthreads();
  }
  store_h2<4, 512>(xl, b1, wr, wc, lane, acc);
  __syncthreads();

  // ---- Lf: 4 slices (stages 9..12), K=256, N=128, NREP=2 ----
  f32x4 acc2[4][2];
#pragma unroll
  for (int m = 0; m < 4; ++m)
#pragma unroll
    for (int n = 0; n < 2; ++n) acc2[m][n] = (f32x4){0.f, 0.f, 0.f, 0.f};
#pragma unroll
  for (int s = 0; s < 4; ++s) {
    const int st = 9 + s;
    if (s < 3) stage_w<128, 256>(w2t, (s + 1) * 64, slot[(st + 1) & 1], wid, lane);
    compute_pair<2, 512>(xl, slot[st & 1], s * 2, wr, wc, lane, acc2);
    asm volatile("s_waitcnt vmcnt(0)" ::: "memory");
    __syncthreads();
  }

  // ---- epilogue: f32 repack into W-ring area (64 KB), streaming stores ----
  float* fl = (float*)(lds + 40960);
  coalesced_out<2, 128, 512>(fl, b2, wr, wc, tid, lane, acc2, e_out,
                             [&](int row) -> long { return (long)(e0 + row); });
}

// ---------------- node kernel (unchanged from r5/r6) ----------------
template <int KSTEPS, int MF, int NREP, int LDB, int WTK>
__device__ __forceinline__ void gemm_layer(const short* lds, const short* Wt,
                                           int wn, int lane, f32x4 acc[MF][NREP]) {
  const int m0 = lane & 15;
  const int g = lane >> 4;
  const short* wp = Wt + (wn * (NREP * 16) + m0) * WTK + g * 8;
  bf16x8 bcur[NREP], bnxt[NREP], a[MF];
#pragma unroll
  for (int n = 0; n < NREP; ++n) bcur[n] = *(const bf16x8*)(wp + n * 16 * WTK);
#pragma unroll
  for (int ks = 0; ks < KSTEPS; ++ks) {
    if (ks + 1 < KSTEPS) {
#pragma unroll
      for (int n = 0; n < NREP; ++n)
        bnxt[n] = *(const bf16x8*)(wp + (ks + 1) * 32 + n * 16 * WTK);
    }
    const int kb = ks * 32 + g * 8;
#pragma unroll
    for (int m = 0; m < MF; ++m) {
      int row = m * 16 + m0;
      int byte = row * LDB + kb * 2;
      byte ^= (row & 7) << 4;
      a[m] = *(const bf16x8*)((const char*)lds + byte);
    }
#pragma unroll
    for (int n = 0; n < NREP; ++n)
#pragma unroll
      for (int m = 0; m < MF; ++m)
        acc[m][n] = __builtin_amdgcn_mfma_f32_16x16x32_bf16(a[m], bcur[n], acc[m][n], 0, 0, 0);
#pragma unroll
    for (int n = 0; n < NREP; ++n) bcur[n] = bnxt[n];
  }
}

template <int MF, int NREP, int LDB>
__device__ __forceinline__ void store_h(short* lds, const float* __restrict__ bias,
                                        int wn, int lane, f32x4 acc[MF][NREP]) {
  const int m0 = lane & 15;
  const int g = lane >> 4;
#pragma unroll
  for (int n = 0; n < NREP; ++n) {
    int col = wn * (NREP * 16) + n * 16 + m0;
    float bv = bias[col];
#pragma unroll
    for (int m = 0; m < MF; ++m) {
#pragma unroll
      for (int j = 0; j < 4; ++j) {
        int row = m * 16 + g * 4 + j;
        float v = acc[m][n][j] + bv;
        v = fmaxf(v, 0.f);
        int byte = row * LDB + col * 2;
        byte ^= (row & 7) << 4;
        *(short*)((char*)lds + byte) = f2bf(v);
      }
    }
  }
}

__global__ __launch_bounds__(512, 4) void node_kernel(
    const short* __restrict__ nbf, const float* __restrict__ e_out,
    const int* __restrict__ basep, const int* __restrict__ eidx,
    const short* __restrict__ wsw,
    const float* __restrict__ b0, const float* __restrict__ b1,
    const float* __restrict__ b2, float* __restrict__ n_out) {
  __shared__ short lds[16384];  // 32 KiB
  const int tid = threadIdx.x;
  const int lane = tid & 63;
  const int wn = tid >> 6;
  const int r0 = blockIdx.x * 64;

#pragma unroll
  for (int i = 0; i < 2; ++i) {
    int task = i * 512 + tid;
    int row = task >> 4;
    int c = task & 15;
    int nrow = r0 + row;
    if (nrow >= NNODES) nrow = NNODES - 1;
    short8 pk = *(const short8*)(nbf + (size_t)nrow * 128 + c * 8);
    int byte = row * 512 + c * 16;
    byte ^= (row & 7) << 4;
    *(short8*)((char*)lds + byte) = pk;
  }

  {
    const int n_local = tid >> 3;
    const int cg = tid & 7;
    const int node = r0 + n_local;
    float sum[16];
#pragma unroll
    for (int q = 0; q < 16; ++q) sum[q] = 0.f;
    if (node < NNODES) {
      int beg = basep[node], end = basep[node + 1];
      for (int j = beg; j < end; ++j) {
        int e = eidx[j];
        const float* er = e_out + (size_t)e * 128 + cg * 16;
#pragma unroll
        for (int q = 0; q < 4; ++q) {
          float4 v = *(const float4*)(er + q * 4);
          sum[q * 4 + 0] += v.x; sum[q * 4 + 1] += v.y;
          sum[q * 4 + 2] += v.z; sum[q * 4 + 3] += v.w;
        }
      }
    }
#pragma unroll
    for (int q = 0; q < 2; ++q) {
      short8 pk;
#pragma unroll
      for (int k = 0; k < 8; ++k) pk[k] = f2bf(sum[q * 8 + k]);
      int col = 128 + cg * 16 + q * 8;
      int byte = n_local * 512 + col * 2;
      byte ^= (n_local & 7) << 4;
      *(short8*)((char*)lds + byte) = pk;
    }
  }
  __syncthreads();

  f32x4 acc[4][2];
#pragma unroll
  for (int m = 0; m < 4; ++m)
#pragma unroll
    for (int n = 0; n < 2; ++n) acc[m][n] = (f32x4){0.f, 0.f, 0.f, 0.f};
  gemm_layer<8, 4, 2, 512, 256>(lds, wsw + OFF_FN_W0T, wn, lane, acc);
  __syncthreads();
  store_h<4, 2, 512>(lds, b0, wn, lane, acc);
  __syncthreads();

#pragma unroll
  for (int m = 0; m < 4; ++m)
#pragma unroll
    for (int n = 0; n < 2; ++n) acc[m][n] = (f32x4){0.f, 0.f, 0.f, 0.f};
  gemm_layer<8, 4, 2, 512, 256>(lds, wsw + OFF_FN_W1T, wn, lane, acc);
  __syncthreads();
  store_h<4, 2, 512>(lds, b1, wn, lane, acc);
  __syncthreads();

  f32x4 acc2[4][1];
#pragma unroll
  for (int m = 0; m < 4; ++m) acc2[m][0] = (f32x4){0.f, 0.f, 0.f, 0.f};
  gemm_layer<8, 4, 1, 512, 256>(lds, wsw + OFF_FN_W2T, wn, lane, acc2);
  __syncthreads();

  coalesced_out<1, 64, 512>((float*)lds, b2, 0, wn, tid, lane, acc2, n_out,
                            [&](int row) -> long {
                              long g = r0 + row;
                              return (g < NNODES) ? g : -1;
                            });
}

// ---------------- prep / CSR (unchanged) ----------------
__global__ void prep_weights_all(const float* __restrict__ w0, const float* __restrict__ w1,
                                 const float* __restrict__ w2, const float* __restrict__ w3,
                                 const float* __restrict__ w4, const float* __restrict__ w5,
                                 short* __restrict__ wsw) {
  const float* src; short* dst; int K, N;
  switch (blockIdx.y) {
    case 0: src = w0; dst = wsw + OFF_FE_W0T; K = 320; N = 256; break;
    case 1: src = w1; dst = wsw + OFF_FE_W1T; K = 256; N = 256; break;
    case 2: src = w2; dst = wsw + OFF_FE_W2T; K = 256; N = 128; break;
    case 3: src = w3; dst = wsw + OFF_FN_W0T; K = 256; N = 256; break;
    case 4: src = w4; dst = wsw + OFF_FN_W1T; K = 256; N = 256; break;
    default: src = w5; dst = wsw + OFF_FN_W2T; K = 256; N = 128; break;
  }
  int idx = blockIdx.x * 256 + threadIdx.x;
  if (idx < K * N) {
    int k = idx / N;
    int n = idx - k * N;
    dst[n * K + k] = f2bf(src[idx]);
  }
}

__global__ void cvt_bf16(const float* __restrict__ src, short* __restrict__ dst, int n8) {
  int i = blockIdx.x * 256 + threadIdx.x;
  if (i < n8) {
    float4 v0 = ((const float4*)src)[i * 2];
    float4 v1 = ((const float4*)src)[i * 2 + 1];
    short8 pk;
    pk[0] = f2bf(v0.x); pk[1] = f2bf(v0.y); pk[2] = f2bf(v0.z); pk[3] = f2bf(v0.w);
    pk[4] = f2bf(v1.x); pk[5] = f2bf(v1.y); pk[6] = f2bf(v1.z); pk[7] = f2bf(v1.w);
    ((short8*)dst)[i] = pk;
  }
}

__global__ void hist_kernel(const int* __restrict__ receivers, int* __restrict__ cnt) {
  int e = blockIdx.x * 512 + threadIdx.x;
  if (e < NEDGES) atomicAdd(&cnt[receivers[e]], 1);
}

__global__ __launch_bounds__(1024) void scan1_kernel(const int* __restrict__ cnt,
                                                     int* __restrict__ base,
                                                     int* __restrict__ bsum) {
  __shared__ int s[1024];
  const int tid = threadIdx.x;
  int i = blockIdx.x * 1024 + tid;
  int v = (i < NNODES) ? cnt[i] : 0;
  s[tid] = v;
  __syncthreads();
  for (int off = 1; off < 1024; off <<= 1) {
    int t = (tid >= off) ? s[tid - off] : 0;
    __syncthreads();
    s[tid] += t;
    __syncthreads();
  }
  if (i < NNODES) base[i] = s[tid] - v;
  if (tid == 1023) bsum[blockIdx.x] = s[1023];
}

__global__ void scan2_kernel(int* __restrict__ bsum, int nblk) {
  if (threadIdx.x == 0) {
    int run = 0;
    for (int b = 0; b < nblk; ++b) { int t = bsum[b]; bsum[b] = run; run += t; }
  }
}

__global__ __launch_bounds__(1024) void scan3_kernel(const int* __restrict__ bsum,
                                                     int* __restrict__ base,
                                                     int* __restrict__ cursor) {
  int i = blockIdx.x * 1024 + threadIdx.x;
  if (i < NNODES) {
    int b = base[i] + bsum[blockIdx.x];
    base[i] = b;
    cursor[i] = b;
  }
  if (i == 0) base[NNODES] = NEDGES;
}

__global__ void scatter_kernel(const int* __restrict__ receivers, int* __restrict__ cursor,
                               int* __restrict__ eidx) {
  int e = blockIdx.x * 512 + threadIdx.x;
  if (e < NEDGES) {
    int pos = atomicAdd(&cursor[receivers[e]], 1);
    eidx[pos] = e;
  }
}

extern "C" void kernel_launch(void* const* d_in, const int* in_sizes, int n_in,
                              void* d_out, int out_size, void* d_ws, size_t ws_size,
                              hipStream_t stream) {
  const float* node_attrs = (const float*)d_in[0];
  const float* edge_attrs = (const float*)d_in[1];
  const int* senders = (const int*)d_in[2];
  const int* receivers = (const int*)d_in[3];
  const float* fe_W0 = (const float*)d_in[4];
  const float* fe_b0 = (const float*)d_in[5];
  const float* fe_W1 = (const float*)d_in[6];
  const float* fe_b1 = (const float*)d_in[7];
  const float* fe_W2 = (const float*)d_in[8];
  const float* fe_b2 = (const float*)d_in[9];
  const float* fn_W0 = (const float*)d_in[10];
  const float* fn_b0 = (const float*)d_in[11];
  const float* fn_W1 = (const float*)d_in[12];
  const float* fn_b1 = (const float*)d_in[13];
  const float* fn_W2 = (const float*)d_in[14];
  const float* fn_b2 = (const float*)d_in[15];

  short* wsw  = (short*)d_ws;
  int* cnt    = (int*)((char*)d_ws + OFF_CNT_B);
  int* basep  = (int*)((char*)d_ws + OFF_BASE_B);
  int* cursor = (int*)((char*)d_ws + OFF_CURSOR_B);
  int* eidx   = (int*)((char*)d_ws + OFF_EIDX_B);
  int* bsum   = (int*)((char*)d_ws + OFF_BSUM_B);
  short* nbf  = (short*)((char*)d_ws + OFF_NBF_B);
  float* out = (float*)d_out;
  float* n_out = out;                                  // [50000][128] first
  float* e_out = out + (size_t)NNODES * 128;           // then [800000][128]

  dim3 gprep(320, 6);
  prep_weights_all<<<gprep, 256, 0, stream>>>(fe_W0, fe_W1, fe_W2, fn_W0, fn_W1, fn_W2, wsw);
  cvt_bf16<<<(NNODES * 128 / 8 + 255) / 256, 256, 0, stream>>>(node_attrs, nbf, NNODES * 128 / 8);
  hipMemsetAsync(cnt, 0, NNODES * sizeof(int), stream);

  const int nscan = (NNODES + 1023) / 1024;   // 49
  hist_kernel<<<(NEDGES + 511) / 512, 512, 0, stream>>>(receivers, cnt);
  scan1_kernel<<<nscan, 1024, 0, stream>>>(cnt, basep, bsum);
  scan2_kernel<<<1, 64, 0, stream>>>(bsum, nscan);
  scan3_kernel<<<nscan, 1024, 0, stream>>>(bsum, basep, cursor);
  scatter_kernel<<<(NEDGES + 511) / 512, 512, 0, stream>>>(receivers, cursor, eidx);

  edge_kernel<<<NEDGES / 128, 512, 0, stream>>>(nbf, edge_attrs, senders, receivers,
                                                wsw, fe_b0, fe_b1, fe_b2, e_out);
  node_kernel<<<(NNODES + 63) / 64, 512, 0, stream>>>(nbf, e_out, basep, eidx, wsw,
                                                      fn_b0, fn_b1, fn_b2, n_out);
}